// Round 1
// 798.758 us; speedup vs baseline: 1.0410x; 1.0410x over previous
//
#include <hip/hip_runtime.h>

#define TPB 256
#define NB1 256    // stripe blocks for edge passes
#define NBUCK 512  // coarse buckets (dst>>8); supports N <= 131072

using half4_t = __attribute__((ext_vector_type(4))) _Float16;
using half8_t = __attribute__((ext_vector_type(8))) _Float16;
using f32x4 = __attribute__((ext_vector_type(4))) float;

// ---------------- CSR build: atomic-free MSD counting sort ----------------

__global__ __launch_bounds__(256) void hist1_k(const int* __restrict__ ei,
                                               int* __restrict__ hist, int E, int stripe) {
  __shared__ int h[NBUCK];
  for (int i = threadIdx.x; i < NBUCK; i += 256) h[i] = 0;
  __syncthreads();
  int b0 = blockIdx.x * stripe;
  int b1 = min(b0 + stripe, E);
  for (int e = b0 + threadIdx.x; e < b1; e += 256) atomicAdd(&h[ei[E + e] >> 8], 1);
  __syncthreads();
  for (int i = threadIdx.x; i < NBUCK; i += 256) hist[i * NB1 + blockIdx.x] = h[i];
}

__global__ void scan1_k(const int* __restrict__ src, int* __restrict__ out,
                        int* __restrict__ chunk, int n) {
  __shared__ int sh[TPB];
  int i = blockIdx.x * TPB + threadIdx.x;
  int v = (i < n) ? src[i] : 0;
  sh[threadIdx.x] = v;
  __syncthreads();
  for (int off = 1; off < TPB; off <<= 1) {
    int t = (threadIdx.x >= off) ? sh[threadIdx.x - off] : 0;
    __syncthreads();
    sh[threadIdx.x] += t;
    __syncthreads();
  }
  if (i < n) out[i] = sh[threadIdx.x] - v;
  if (threadIdx.x == TPB - 1) chunk[blockIdx.x] = sh[TPB - 1];
}

__global__ void scan2_k(int* __restrict__ chunk, int nb) {
  __shared__ int sh[512];
  int v = (threadIdx.x < nb) ? chunk[threadIdx.x] : 0;
  sh[threadIdx.x] = v;
  __syncthreads();
  for (int off = 1; off < 512; off <<= 1) {
    int t = (threadIdx.x >= off) ? sh[threadIdx.x - off] : 0;
    __syncthreads();
    sh[threadIdx.x] += t;
    __syncthreads();
  }
  if (threadIdx.x < nb) chunk[threadIdx.x] = sh[threadIdx.x] - v;
}

__global__ void scan3_k(int* __restrict__ out, const int* __restrict__ chunk, int n) {
  int i = blockIdx.x * TPB + threadIdx.x;
  if (i < n) out[i] += chunk[blockIdx.x];
}

// pack: src (24 bits) | low8(dst) << 24
__global__ __launch_bounds__(256) void scatter1_k(const int* __restrict__ ei,
                                                  const int* __restrict__ base,
                                                  unsigned* __restrict__ ebuf, int E,
                                                  int stripe) {
  __shared__ int cur[NBUCK];
  for (int i = threadIdx.x; i < NBUCK; i += 256) cur[i] = base[i * NB1 + blockIdx.x];
  __syncthreads();
  int b0 = blockIdx.x * stripe;
  int b1 = min(b0 + stripe, E);
  for (int e = b0 + threadIdx.x; e < b1; e += 256) {
    int s = ei[e];
    int d = ei[E + e];
    int p = atomicAdd(&cur[d >> 8], 1);
    ebuf[p] = (unsigned)s | ((unsigned)(d & 255) << 24);
  }
}

__global__ __launch_bounds__(256) void build_k(const unsigned* __restrict__ ebuf,
                                               const int* __restrict__ base,
                                               int* __restrict__ row_start,
                                               int* __restrict__ deg,
                                               float* __restrict__ invd,
                                               int* __restrict__ csr, int N, int E) {
  __shared__ int h[256];
  __shared__ int excl[256];
  __shared__ int bse[2];
  int b = blockIdx.x;
  int t = threadIdx.x;
  if (t == 0) {
    bse[0] = base[b * NB1];
    bse[1] = (b + 1 < NBUCK) ? base[(b + 1) * NB1] : E;
  }
  h[t] = 0;
  __syncthreads();
  int bs = bse[0], be = bse[1];
  for (int e = bs + t; e < be; e += 256) atomicAdd(&h[ebuf[e] >> 24], 1);
  __syncthreads();
  int v = h[t];
  excl[t] = v;
  __syncthreads();
  for (int off = 1; off < 256; off <<= 1) {
    int tv = (t >= off) ? excl[t - off] : 0;
    __syncthreads();
    excl[t] += tv;
    __syncthreads();
  }
  int ex = excl[t] - v;
  int node = b * 256 + t;
  if (node < N) {
    row_start[node] = bs + ex;
    deg[node] = v;
    invd[node] = 1.0f / fmaxf((float)v, 1.0f);
  }
  h[t] = bs + ex;
  __syncthreads();
  for (int e = bs + t; e < be; e += 256) {
    unsigned p = ebuf[e];
    int pos = atomicAdd(&h[p >> 24], 1);
    csr[pos] = (int)(p & 0xFFFFFFu);
  }
}

// ---------------- fp32 -> fp16 converts ----------------

__global__ void f2h_k(const float* __restrict__ in, _Float16* __restrict__ out, int n4) {
  int i = blockIdx.x * TPB + threadIdx.x;
  if (i < n4) {
    float4 v = ((const float4*)in)[i];
    half4_t o;
    o.x = (_Float16)v.x; o.y = (_Float16)v.y; o.z = (_Float16)v.z; o.w = (_Float16)v.w;
    ((half4_t*)out)[i] = o;
  }
}

// Convert the 6 layer weight matrices (each 128x128) to fp16, packed
// [W1l, W1r, W2l, W2r, W3l, W3r] at 16384-element strides.
__global__ void w6_k(const float* __restrict__ w0, const float* __restrict__ w1,
                     const float* __restrict__ w2, const float* __restrict__ w3,
                     const float* __restrict__ w4, const float* __restrict__ w5,
                     _Float16* __restrict__ out) {
  int t = blockIdx.x * TPB + threadIdx.x;  // t < 6*4096 (float4 units)
  if (t >= 6 * 4096) return;
  int which = t >> 12, i = t & 4095;
  const float* src = which == 0 ? w0 : which == 1 ? w1 : which == 2 ? w2
                   : which == 3 ? w3 : which == 4 ? w4 : w5;
  float4 v = ((const float4*)src)[i];
  half4_t o;
  o.x = (_Float16)v.x; o.y = (_Float16)v.y; o.z = (_Float16)v.z; o.w = (_Float16)v.w;
  ((half4_t*)out)[(size_t)which * 4096 + i] = o;
}

// ---------------- 128-dim mean aggregation, fp16 gather, fp16 out ----------------
// One wave per node. Lane layout: g = lane>>4 picks one of 4 edge slots,
// l = lane&15 covers features l*8..l*8+7 via half8 (16 B) loads.
// Each gather instruction pulls 4 full 256 B rows (4 edges); main loop keeps
// 4 such loads (4 KB) in flight per wave and prefetches the next chunk's csr
// indices before accumulating, so idx latency stays off the critical path.
// Tail is branch-free: clamp the csr index and fma with a 0/1 mask, so a
// low-degree node costs 2 round trips instead of a serial per-edge chain.

__global__ __launch_bounds__(256) void agg128_k(const _Float16* __restrict__ hb,
                                                const int* __restrict__ csr,
                                                const int* __restrict__ row_start,
                                                const int* __restrict__ deg,
                                                const float* __restrict__ invd,
                                                _Float16* __restrict__ out, int n) {
  int node = (blockIdx.x << 2) + (threadIdx.x >> 6);
  if (node >= n) return;
  int lane = threadIdx.x & 63;
  int g = lane >> 4;  // edge slot 0..3
  int l = lane & 15;  // feature lane
  int s = row_start[node];
  int c = deg[node];
  const _Float16* base = hb + (l << 3);
  float a0 = 0.f, a1 = 0.f, a2 = 0.f, a3 = 0.f;
  float a4 = 0.f, a5 = 0.f, a6 = 0.f, a7 = 0.f;
  int j = 0;
  if (c >= 16) {
    int id[4];
#pragma unroll
    for (int p = 0; p < 4; ++p) id[p] = csr[s + 4 * p + g];
    while (true) {
      half8_t v[4];
#pragma unroll
      for (int p = 0; p < 4; ++p) v[p] = *(const half8_t*)&base[(size_t)id[p] * 128];
      j += 16;
      bool more = (j + 16 <= c);
      if (more) {
#pragma unroll
        for (int p = 0; p < 4; ++p) id[p] = csr[s + j + 4 * p + g];
      }
#pragma unroll
      for (int p = 0; p < 4; ++p) {
        a0 += (float)v[p][0]; a1 += (float)v[p][1];
        a2 += (float)v[p][2]; a3 += (float)v[p][3];
        a4 += (float)v[p][4]; a5 += (float)v[p][5];
        a6 += (float)v[p][6]; a7 += (float)v[p][7];
      }
      if (!more) break;
    }
  }
  // masked tail: remaining 0..15 edges, all loads issued together
  if (j < c) {
    int cm1 = c - 1;
#pragma unroll
    for (int p = 0; p < 4; ++p) {
      int e = j + 4 * p + g;
      float m = (e < c) ? 1.f : 0.f;
      int id = csr[s + min(e, cm1)];
      half8_t v = *(const half8_t*)&base[(size_t)id * 128];
      a0 = fmaf(m, (float)v[0], a0); a1 = fmaf(m, (float)v[1], a1);
      a2 = fmaf(m, (float)v[2], a2); a3 = fmaf(m, (float)v[3], a3);
      a4 = fmaf(m, (float)v[4], a4); a5 = fmaf(m, (float)v[5], a5);
      a6 = fmaf(m, (float)v[6], a6); a7 = fmaf(m, (float)v[7], a7);
    }
  }
  // reduce across the 4 edge slots (lanes l, l+16, l+32, l+48)
  a0 += __shfl_xor(a0, 16); a1 += __shfl_xor(a1, 16);
  a2 += __shfl_xor(a2, 16); a3 += __shfl_xor(a3, 16);
  a4 += __shfl_xor(a4, 16); a5 += __shfl_xor(a5, 16);
  a6 += __shfl_xor(a6, 16); a7 += __shfl_xor(a7, 16);
  a0 += __shfl_xor(a0, 32); a1 += __shfl_xor(a1, 32);
  a2 += __shfl_xor(a2, 32); a3 += __shfl_xor(a3, 32);
  a4 += __shfl_xor(a4, 32); a5 += __shfl_xor(a5, 32);
  a6 += __shfl_xor(a6, 32); a7 += __shfl_xor(a7, 32);
  if (g == 0) {
    float w = invd[node];
    half8_t r;
    r[0] = (_Float16)(a0 * w); r[1] = (_Float16)(a1 * w);
    r[2] = (_Float16)(a2 * w); r[3] = (_Float16)(a3 * w);
    r[4] = (_Float16)(a4 * w); r[5] = (_Float16)(a5 * w);
    r[6] = (_Float16)(a6 * w); r[7] = (_Float16)(a7 * w);
    *(half8_t*)&out[(size_t)node * 128 + (l << 3)] = r;
  }
}

// ---------------- fused dual GEMM via f16 MFMA ----------------
// outh = act(Aagg@Wl^T + Ah@Wr^T + b), fp32 accumulate, fp16 store.
// Block: 4 waves; wave = 16-row strip x 128 cols (8 col-tiles of 16x16x32 MFMA).
// A frag: lane holds A[m=lane&15][k=quad*8+j]; B frag: W[o=lane&15 of tile][same k].
// C/D: col=lane&15, row=quad*4+reg (m89-verified).

__global__ __launch_bounds__(256) void gemm2_k(
    const _Float16* __restrict__ Aagg, const _Float16* __restrict__ Ah,
    const _Float16* __restrict__ Wh,  // [2][128][128]: Wl then Wr
    const float* __restrict__ bias, _Float16* __restrict__ outh, int n, int do_relu) {
  int wave = threadIdx.x >> 6;
  int lane = threadIdx.x & 63;
  int quad = lane >> 4;
  int l16 = lane & 15;
  int m0 = blockIdx.x * 64 + wave * 16;
  int arow = m0 + l16;
  bool valid = arow < n;
  size_t abase = (size_t)arow * 128 + quad * 8;

  f32x4 acc[8];
#pragma unroll
  for (int c = 0; c < 8; ++c) acc[c] = (f32x4){0.f, 0.f, 0.f, 0.f};

#pragma unroll
  for (int s = 0; s < 2; ++s) {
    const _Float16* A = s ? Ah : Aagg;
    const _Float16* W = Wh + (size_t)s * 16384;
#pragma unroll
    for (int kb = 0; kb < 128; kb += 32) {
      half8_t af;
      if (valid) {
        af = *(const half8_t*)&A[abase + kb];
      } else {
#pragma unroll
        for (int jj = 0; jj < 8; ++jj) af[jj] = (_Float16)0;
      }
#pragma unroll
      for (int c = 0; c < 8; ++c) {
        half8_t bf = *(const half8_t*)&W[(size_t)(c * 16 + l16) * 128 + kb + quad * 8];
        acc[c] = __builtin_amdgcn_mfma_f32_16x16x32_f16(af, bf, acc[c], 0, 0, 0);
      }
    }
  }

#pragma unroll
  for (int c = 0; c < 8; ++c) {
    float bcol = bias[c * 16 + l16];
#pragma unroll
    for (int r = 0; r < 4; ++r) {
      int row = m0 + quad * 4 + r;
      if (row < n) {
        float v = acc[c][r] + bcol;
        if (do_relu) v = fmaxf(v, 0.f);
        outh[(size_t)row * 128 + c * 16 + l16] = (_Float16)v;
      }
    }
  }
}

// ---------------- head weight packing (fp16 Wcat, fp32 bcat) ----------------

__global__ void pack_head_k(const float* __restrict__ Wal, const float* __restrict__ War,
                            const float* __restrict__ ba, const float* __restrict__ Wsl,
                            const float* __restrict__ Wsr, const float* __restrict__ bsx,
                            const float* __restrict__ Wel, const float* __restrict__ Wer,
                            const float* __restrict__ be, _Float16* __restrict__ Wcat,
                            float* __restrict__ bcat) {
  int t = blockIdx.x * TPB + threadIdx.x;
  float v = 0.f;
  bool ok = t < 2048;
  if (t < 384) v = Wal[t];
  else if (t < 640) v = Wsl[t - 384];
  else if (t < 1024) v = Wel[t - 640];
  else if (t < 1408) v = War[t - 1024];
  else if (t < 1664) v = Wsr[t - 1408];
  else if (t < 2048) v = Wer[t - 1664];
  if (ok) Wcat[t] = (_Float16)v;
  if (t < 16) {
    float b = 0.f;
    if (t >= 8 && t < 11) b = ba[t - 8];
    else if (t >= 11 && t < 13) b = bsx[t - 11];
    else if (t >= 13) b = be[t - 13];
    bcat[t] = b;
  }
}

// ---------------- head GEMM: out_lr[n,16] = h3 @ Wcat^T + bcat (fp16 in) ----------------

__global__ __launch_bounds__(256) void head_gemm_k(const _Float16* __restrict__ h,
                                                   const _Float16* __restrict__ Wcat,
                                                   const float* __restrict__ bcat,
                                                   float* __restrict__ out_lr, int n) {
  __shared__ float hs[64 * 132];
  __shared__ float Ws[16 * 128];
  __shared__ float bsh[16];
  int tid = threadIdx.x;
  int m0 = blockIdx.x * 64;
  {
    half8_t w = *(const half8_t*)&Wcat[tid * 8];
#pragma unroll
    for (int jj = 0; jj < 8; ++jj) Ws[tid * 8 + jj] = (float)w[jj];
    if (tid < 16) bsh[tid] = bcat[tid];
  }
  {
    int row = tid >> 2, q = tid & 3;
    int grow = m0 + row;
#pragma unroll
    for (int j = 0; j < 4; ++j) {
      half8_t v;
      if (grow < n) {
        v = *(const half8_t*)&h[(size_t)grow * 128 + q * 32 + j * 8];
      } else {
#pragma unroll
        for (int jj = 0; jj < 8; ++jj) v[jj] = (_Float16)0;
      }
#pragma unroll
      for (int jj = 0; jj < 8; ++jj) hs[row * 132 + q * 32 + j * 8 + jj] = (float)v[jj];
    }
  }
  __syncthreads();
  int row = tid & 63, og = tid >> 6;
  float acc[4] = {0.f, 0.f, 0.f, 0.f};
#pragma unroll
  for (int k4 = 0; k4 < 32; ++k4) {
    float4 hv = *(float4*)&hs[row * 132 + k4 * 4];
#pragma unroll
    for (int i = 0; i < 4; ++i) {
      float4 wv = *(float4*)&Ws[(og * 4 + i) * 128 + k4 * 4];
      acc[i] += hv.x * wv.x + hv.y * wv.y + hv.z * wv.z + hv.w * wv.w;
    }
  }
  int grow = m0 + row;
  if (grow < n) {
#pragma unroll
    for (int i = 0; i < 4; ++i)
      out_lr[(size_t)grow * 16 + og * 4 + i] = acc[i] + bsh[og * 4 + i];
  }
}

// ---------------- 8-dim aggregation + output write ----------------
// out layout: age [n,3] @0, sex [n,2] @3n, eth [n,3] @5n
// Lane layout: g = lane>>2 picks one of 16 edge slots; c2 = lane&3 covers
// features 2*c2, 2*c2+1 via float2 loads. One instruction gathers 16 rows;
// main loop keeps 2 (32 edges) in flight. Branch-free masked tail.

__global__ void agg8_k(const float* __restrict__ hlr, const int* __restrict__ csr,
                       const int* __restrict__ row_start, const int* __restrict__ deg,
                       const float* __restrict__ invd, float* __restrict__ out, int n) {
  int node = (blockIdx.x << 2) + (threadIdx.x >> 6);
  if (node >= n) return;
  int lane = threadIdx.x & 63;
  int c2 = lane & 3;  // feature pair
  int g = lane >> 2;  // edge slot 0..15
  int s = row_start[node], cnt = deg[node];
  float ax = 0.f, ay = 0.f;
  int j = 0;
  for (; j + 32 <= cnt; j += 32) {
#pragma unroll
    for (int p = 0; p < 2; ++p) {
      int id = csr[s + j + 16 * p + g];
      float2 v = *(const float2*)&hlr[(size_t)id * 16 + 2 * c2];
      ax += v.x;
      ay += v.y;
    }
  }
  if (j < cnt) {
    int cm1 = cnt - 1;
#pragma unroll
    for (int p = 0; p < 2; ++p) {
      int e = j + 16 * p + g;
      float m = (e < cnt) ? 1.f : 0.f;
      int id = csr[s + min(e, cm1)];
      float2 v = *(const float2*)&hlr[(size_t)id * 16 + 2 * c2];
      ax = fmaf(m, v.x, ax);
      ay = fmaf(m, v.y, ay);
    }
  }
  ax += __shfl_xor(ax, 4);  ay += __shfl_xor(ay, 4);
  ax += __shfl_xor(ax, 8);  ay += __shfl_xor(ay, 8);
  ax += __shfl_xor(ax, 16); ay += __shfl_xor(ay, 16);
  ax += __shfl_xor(ax, 32); ay += __shfl_xor(ay, 32);
  if (g == 0) {
    float w = invd[node];
    float r0 = ax * w + hlr[(size_t)node * 16 + 8 + 2 * c2];
    float r1 = ay * w + hlr[(size_t)node * 16 + 8 + 2 * c2 + 1];
    float rr[2] = {r0, r1};
#pragma unroll
    for (int q = 0; q < 2; ++q) {
      int f = 2 * c2 + q;
      float r = rr[q];
      if (f < 3) out[(size_t)node * 3 + f] = r;
      else if (f < 5) out[(size_t)3 * n + (size_t)node * 2 + (f - 3)] = r;
      else out[(size_t)5 * n + (size_t)node * 3 + (f - 5)] = r;
    }
  }
}

// ---------------- launch ----------------

extern "C" void kernel_launch(void* const* d_in, const int* in_sizes, int n_in,
                              void* d_out, int out_size, void* d_ws, size_t ws_size,
                              hipStream_t stream) {
  const float* x = (const float*)d_in[0];
  const int* ei = (const int*)d_in[1];
  const float* W1l = (const float*)d_in[2];
  const float* W1r = (const float*)d_in[3];
  const float* b1 = (const float*)d_in[4];
  const float* W2l = (const float*)d_in[5];
  const float* W2r = (const float*)d_in[6];
  const float* b2 = (const float*)d_in[7];
  const float* W3l = (const float*)d_in[8];
  const float* W3r = (const float*)d_in[9];
  const float* b3 = (const float*)d_in[10];
  const float* Wal = (const float*)d_in[11];
  const float* War = (const float*)d_in[12];
  const float* ba = (const float*)d_in[13];
  const float* Wsl = (const float*)d_in[14];
  const float* Wsr = (const float*)d_in[15];
  const float* bsx = (const float*)d_in[16];
  const float* Wel = (const float*)d_in[17];
  const float* Wer = (const float*)d_in[18];
  const float* be = (const float*)d_in[19];

  int N = in_sizes[0] / 128;
  int E = in_sizes[1] / 2;
  int NBKT = (N + 255) >> 8;

  char* w = (char*)d_ws;
  auto alloc = [&](size_t b) {
    char* p = w;
    w += (b + 255) & ~(size_t)255;
    return p;
  };
  int* deg = (int*)alloc((size_t)N * 4);
  int* row_start = (int*)alloc((size_t)N * 4);
  float* invd = (float*)alloc((size_t)N * 4);
  int* hist = (int*)alloc((size_t)NBUCK * NB1 * 4);
  int* chunk = (int*)alloc(512 * 4);
  int* csr = (int*)alloc((size_t)E * 4);
  // xh (fp16 x, N*128*2 B) aliases ebuf (E*4 B): ebuf dead after build_k.
  size_t xh_bytes = (size_t)N * 128 * 2;
  size_t ebuf_bytes = (size_t)E * 4;
  char* region = (char*)alloc(xh_bytes > ebuf_bytes ? xh_bytes : ebuf_bytes);
  unsigned* ebuf = (unsigned*)region;
  _Float16* xh = (_Float16*)region;
  _Float16* aggh = (_Float16*)alloc((size_t)N * 128 * 2);
  _Float16* hA = (_Float16*)alloc((size_t)N * 128 * 2);
  _Float16* hB = (_Float16*)alloc((size_t)N * 128 * 2);
  _Float16* wh = (_Float16*)alloc((size_t)6 * 16384 * 2);
  _Float16* Wcat = (_Float16*)alloc(2048 * 2);
  float* bcat = (float*)alloc(16 * 4);
  float* head_lr = (float*)alloc((size_t)N * 16 * 4);

  int stripe = (((E + NB1 - 1) / NB1) + 255) & ~255;
  int nscan = NBUCK * NB1;
  int nbScan = (nscan + TPB - 1) / TPB;
  int nbNode = (N + 3) / 4;
  int nbM = (N + 63) / 64;
  int nbC = (N * 32 + TPB - 1) / TPB;

  // CSR build — no global atomics
  hist1_k<<<NB1, 256, 0, stream>>>(ei, hist, E, stripe);
  scan1_k<<<nbScan, TPB, 0, stream>>>(hist, hist, chunk, nscan);
  scan2_k<<<1, 512, 0, stream>>>(chunk, nbScan);
  scan3_k<<<nbScan, TPB, 0, stream>>>(hist, chunk, nscan);
  scatter1_k<<<NB1, 256, 0, stream>>>(ei, hist, ebuf, E, stripe);
  build_k<<<NBKT, 256, 0, stream>>>(ebuf, hist, row_start, deg, invd, csr, N, E);

  // fp16 conversions (xh aliases ebuf: must come after build_k)
  f2h_k<<<nbC, TPB, 0, stream>>>(x, xh, N * 32);
  w6_k<<<96, TPB, 0, stream>>>(W1l, W1r, W2l, W2r, W3l, W3r, wh);
  pack_head_k<<<8, TPB, 0, stream>>>(Wal, War, ba, Wsl, Wsr, bsx, Wel, Wer, be, Wcat, bcat);

  // layer 1: x -> hA
  agg128_k<<<nbNode, TPB, 0, stream>>>(xh, csr, row_start, deg, invd, aggh, N);
  gemm2_k<<<nbM, TPB, 0, stream>>>(aggh, xh, wh + 0 * 16384, b1, hA, N, 1);
  // layer 2: hA -> hB
  agg128_k<<<nbNode, TPB, 0, stream>>>(hA, csr, row_start, deg, invd, aggh, N);
  gemm2_k<<<nbM, TPB, 0, stream>>>(aggh, hA, wh + 2 * 16384, b2, hB, N, 1);
  // layer 3: hB -> hA (hA layer-1 copy dead)
  agg128_k<<<nbNode, TPB, 0, stream>>>(hB, csr, row_start, deg, invd, aggh, N);
  gemm2_k<<<nbM, TPB, 0, stream>>>(aggh, hB, wh + 4 * 16384, b3, hA, N, 1);
  // heads: transform to 16 dims first, then aggregate
  head_gemm_k<<<nbM, TPB, 0, stream>>>(hA, Wcat, bcat, head_lr, N);
  agg8_k<<<nbNode, TPB, 0, stream>>>(head_lr, csr, row_start, deg, invd, (float*)d_out, N);
}

// Round 2
// 782.326 us; speedup vs baseline: 1.0629x; 1.0210x over previous
//
#include <hip/hip_runtime.h>

#define TPB 256
#define NB1 256    // stripe blocks for edge passes
#define NBUCK 512  // coarse buckets (dst>>8); supports N <= 131072

using half4_t = __attribute__((ext_vector_type(4))) _Float16;
using half8_t = __attribute__((ext_vector_type(8))) _Float16;
using f32x4 = __attribute__((ext_vector_type(4))) float;

// ---------------- CSR build: atomic-free MSD counting sort ----------------

__global__ __launch_bounds__(256) void hist1_k(const int* __restrict__ ei,
                                               int* __restrict__ hist, int E, int stripe) {
  __shared__ int h[NBUCK];
  for (int i = threadIdx.x; i < NBUCK; i += 256) h[i] = 0;
  __syncthreads();
  int b0 = blockIdx.x * stripe;
  int b1 = min(b0 + stripe, E);
  for (int e = b0 + threadIdx.x; e < b1; e += 256) atomicAdd(&h[ei[E + e] >> 8], 1);
  __syncthreads();
  for (int i = threadIdx.x; i < NBUCK; i += 256) hist[i * NB1 + blockIdx.x] = h[i];
}

__global__ void scan1_k(const int* __restrict__ src, int* __restrict__ out,
                        int* __restrict__ chunk, int n) {
  __shared__ int sh[TPB];
  int i = blockIdx.x * TPB + threadIdx.x;
  int v = (i < n) ? src[i] : 0;
  sh[threadIdx.x] = v;
  __syncthreads();
  for (int off = 1; off < TPB; off <<= 1) {
    int t = (threadIdx.x >= off) ? sh[threadIdx.x - off] : 0;
    __syncthreads();
    sh[threadIdx.x] += t;
    __syncthreads();
  }
  if (i < n) out[i] = sh[threadIdx.x] - v;
  if (threadIdx.x == TPB - 1) chunk[blockIdx.x] = sh[TPB - 1];
}

__global__ void scan2_k(int* __restrict__ chunk, int nb) {
  __shared__ int sh[512];
  int v = (threadIdx.x < nb) ? chunk[threadIdx.x] : 0;
  sh[threadIdx.x] = v;
  __syncthreads();
  for (int off = 1; off < 512; off <<= 1) {
    int t = (threadIdx.x >= off) ? sh[threadIdx.x - off] : 0;
    __syncthreads();
    sh[threadIdx.x] += t;
    __syncthreads();
  }
  if (threadIdx.x < nb) chunk[threadIdx.x] = sh[threadIdx.x] - v;
}

__global__ void scan3_k(int* __restrict__ out, const int* __restrict__ chunk, int n) {
  int i = blockIdx.x * TPB + threadIdx.x;
  if (i < n) out[i] += chunk[blockIdx.x];
}

// pack: src (24 bits) | low8(dst) << 24
__global__ __launch_bounds__(256) void scatter1_k(const int* __restrict__ ei,
                                                  const int* __restrict__ base,
                                                  unsigned* __restrict__ ebuf, int E,
                                                  int stripe) {
  __shared__ int cur[NBUCK];
  for (int i = threadIdx.x; i < NBUCK; i += 256) cur[i] = base[i * NB1 + blockIdx.x];
  __syncthreads();
  int b0 = blockIdx.x * stripe;
  int b1 = min(b0 + stripe, E);
  for (int e = b0 + threadIdx.x; e < b1; e += 256) {
    int s = ei[e];
    int d = ei[E + e];
    int p = atomicAdd(&cur[d >> 8], 1);
    ebuf[p] = (unsigned)s | ((unsigned)(d & 255) << 24);
  }
}

__global__ __launch_bounds__(256) void build_k(const unsigned* __restrict__ ebuf,
                                               const int* __restrict__ base,
                                               int* __restrict__ row_start,
                                               int* __restrict__ deg,
                                               float* __restrict__ invd,
                                               int* __restrict__ csr, int N, int E) {
  __shared__ int h[256];
  __shared__ int excl[256];
  __shared__ int bse[2];
  int b = blockIdx.x;
  int t = threadIdx.x;
  if (t == 0) {
    bse[0] = base[b * NB1];
    bse[1] = (b + 1 < NBUCK) ? base[(b + 1) * NB1] : E;
  }
  h[t] = 0;
  __syncthreads();
  int bs = bse[0], be = bse[1];
  for (int e = bs + t; e < be; e += 256) atomicAdd(&h[ebuf[e] >> 24], 1);
  __syncthreads();
  int v = h[t];
  excl[t] = v;
  __syncthreads();
  for (int off = 1; off < 256; off <<= 1) {
    int tv = (t >= off) ? excl[t - off] : 0;
    __syncthreads();
    excl[t] += tv;
    __syncthreads();
  }
  int ex = excl[t] - v;
  int node = b * 256 + t;
  if (node < N) {
    row_start[node] = bs + ex;
    deg[node] = v;
    invd[node] = 1.0f / fmaxf((float)v, 1.0f);
  }
  h[t] = bs + ex;
  __syncthreads();
  for (int e = bs + t; e < be; e += 256) {
    unsigned p = ebuf[e];
    int pos = atomicAdd(&h[p >> 24], 1);
    csr[pos] = (int)(p & 0xFFFFFFu);
  }
}

// ---------------- fp32 -> fp16 converts ----------------

__global__ void f2h_k(const float* __restrict__ in, _Float16* __restrict__ out, int n4) {
  int i = blockIdx.x * TPB + threadIdx.x;
  if (i < n4) {
    float4 v = ((const float4*)in)[i];
    half4_t o;
    o.x = (_Float16)v.x; o.y = (_Float16)v.y; o.z = (_Float16)v.z; o.w = (_Float16)v.w;
    ((half4_t*)out)[i] = o;
  }
}

// Convert the 6 layer weight matrices (each 128x128) to fp16, packed
// [W1l, W1r, W2l, W2r, W3l, W3r] at 16384-element strides.
__global__ void w6_k(const float* __restrict__ w0, const float* __restrict__ w1,
                     const float* __restrict__ w2, const float* __restrict__ w3,
                     const float* __restrict__ w4, const float* __restrict__ w5,
                     _Float16* __restrict__ out) {
  int t = blockIdx.x * TPB + threadIdx.x;  // t < 6*4096 (float4 units)
  if (t >= 6 * 4096) return;
  int which = t >> 12, i = t & 4095;
  const float* src = which == 0 ? w0 : which == 1 ? w1 : which == 2 ? w2
                   : which == 3 ? w3 : which == 4 ? w4 : w5;
  float4 v = ((const float4*)src)[i];
  half4_t o;
  o.x = (_Float16)v.x; o.y = (_Float16)v.y; o.z = (_Float16)v.z; o.w = (_Float16)v.w;
  ((half4_t*)out)[(size_t)which * 4096 + i] = o;
}

// ---------------- head weight packing (fp16 Wcat, fp32 bcat) ----------------

__global__ void pack_head_k(const float* __restrict__ Wal, const float* __restrict__ War,
                            const float* __restrict__ ba, const float* __restrict__ Wsl,
                            const float* __restrict__ Wsr, const float* __restrict__ bsx,
                            const float* __restrict__ Wel, const float* __restrict__ Wer,
                            const float* __restrict__ be, _Float16* __restrict__ Wcat,
                            float* __restrict__ bcat) {
  int t = blockIdx.x * TPB + threadIdx.x;
  float v = 0.f;
  bool ok = t < 2048;
  if (t < 384) v = Wal[t];
  else if (t < 640) v = Wsl[t - 384];
  else if (t < 1024) v = Wel[t - 640];
  else if (t < 1408) v = War[t - 1024];
  else if (t < 1664) v = Wsr[t - 1408];
  else if (t < 2048) v = Wer[t - 1664];
  if (ok) Wcat[t] = (_Float16)v;
  if (t < 16) {
    float b = 0.f;
    if (t >= 8 && t < 11) b = ba[t - 8];
    else if (t >= 11 && t < 13) b = bsx[t - 11];
    else if (t >= 13) b = be[t - 13];
    bcat[t] = b;
  }
}

// ---------------- fused SAGE layer: gather-mean -> LDS -> dual MFMA GEMM ----------------
// Block = 4 waves = 64-node tile.
// Phase 1 (gather): each wave mean-aggregates its 16 nodes into LDS A-tile.
//   Lane layout per node: g=lane>>4 picks edge slot 0..3, l=lane&15 covers
//   features l*8..l*8+7 (half8, 16 B). 4 rows/instruction, 4 KB in flight.
// Phase 2 (GEMM): wave computes 16x128 output strip via 16x16x32 f16 MFMA:
//   s=0 operand A from LDS (agg), s=1 from global (root h). C layout:
//   col=lane&15, row=quad*4+reg (m89-verified).
// mode 0: out = relu(...) -> hout (fp16 [n][128])
// mode 1: h3 = relu(...); head_out[n][16] = h3 @ Wcat^T + bcat (fp32)
// LDS row stride 144 halfs (288 B): 16B-aligned, 4-way-max bank aliasing.

__global__ __launch_bounds__(256) void fused_sage_k(
    const _Float16* __restrict__ hin, const _Float16* __restrict__ Wh,
    const float* __restrict__ bias, const int* __restrict__ csr,
    const int* __restrict__ row_start, const int* __restrict__ deg,
    const float* __restrict__ invd, _Float16* __restrict__ hout,
    const _Float16* __restrict__ Wcat, const float* __restrict__ bcat,
    float* __restrict__ head_out, int n, int mode) {
  __shared__ _Float16 At[64][144];
  int wave = threadIdx.x >> 6;
  int lane = threadIdx.x & 63;
  int g = lane >> 4;  // edge slot / quad
  int l = lane & 15;  // feature lane / l16
  int ms = blockIdx.x * 64 + wave * 16;  // wave's strip base row

  // ---- phase 1: mean-aggregate 16 nodes into LDS strip ----
  const _Float16* gbase = hin + (l << 3);
  for (int i = 0; i < 16; ++i) {
    int node = ms + i;
    float a0 = 0.f, a1 = 0.f, a2 = 0.f, a3 = 0.f;
    float a4 = 0.f, a5 = 0.f, a6 = 0.f, a7 = 0.f;
    if (node < n) {
      int s = row_start[node];
      int c = deg[node];
      int j = 0;
      if (c >= 16) {
        int id[4];
#pragma unroll
        for (int p = 0; p < 4; ++p) id[p] = csr[s + 4 * p + g];
        while (true) {
          half8_t v[4];
#pragma unroll
          for (int p = 0; p < 4; ++p) v[p] = *(const half8_t*)&gbase[(size_t)id[p] * 128];
          j += 16;
          bool more = (j + 16 <= c);
          if (more) {
#pragma unroll
            for (int p = 0; p < 4; ++p) id[p] = csr[s + j + 4 * p + g];
          }
#pragma unroll
          for (int p = 0; p < 4; ++p) {
            a0 += (float)v[p][0]; a1 += (float)v[p][1];
            a2 += (float)v[p][2]; a3 += (float)v[p][3];
            a4 += (float)v[p][4]; a5 += (float)v[p][5];
            a6 += (float)v[p][6]; a7 += (float)v[p][7];
          }
          if (!more) break;
        }
      }
      if (j < c) {  // masked tail: 0..15 edges, all loads issued together
        int cm1 = c - 1;
#pragma unroll
        for (int p = 0; p < 4; ++p) {
          int e = j + 4 * p + g;
          float m = (e < c) ? 1.f : 0.f;
          int id = csr[s + min(e, cm1)];
          half8_t v = *(const half8_t*)&gbase[(size_t)id * 128];
          a0 = fmaf(m, (float)v[0], a0); a1 = fmaf(m, (float)v[1], a1);
          a2 = fmaf(m, (float)v[2], a2); a3 = fmaf(m, (float)v[3], a3);
          a4 = fmaf(m, (float)v[4], a4); a5 = fmaf(m, (float)v[5], a5);
          a6 = fmaf(m, (float)v[6], a6); a7 = fmaf(m, (float)v[7], a7);
        }
      }
    }
    // reduce across the 4 edge slots (lanes l, l+16, l+32, l+48)
    a0 += __shfl_xor(a0, 16); a1 += __shfl_xor(a1, 16);
    a2 += __shfl_xor(a2, 16); a3 += __shfl_xor(a3, 16);
    a4 += __shfl_xor(a4, 16); a5 += __shfl_xor(a5, 16);
    a6 += __shfl_xor(a6, 16); a7 += __shfl_xor(a7, 16);
    a0 += __shfl_xor(a0, 32); a1 += __shfl_xor(a1, 32);
    a2 += __shfl_xor(a2, 32); a3 += __shfl_xor(a3, 32);
    a4 += __shfl_xor(a4, 32); a5 += __shfl_xor(a5, 32);
    a6 += __shfl_xor(a6, 32); a7 += __shfl_xor(a7, 32);
    if (g == 0) {
      float w = (node < n) ? invd[node] : 0.f;
      half8_t r;
      r[0] = (_Float16)(a0 * w); r[1] = (_Float16)(a1 * w);
      r[2] = (_Float16)(a2 * w); r[3] = (_Float16)(a3 * w);
      r[4] = (_Float16)(a4 * w); r[5] = (_Float16)(a5 * w);
      r[6] = (_Float16)(a6 * w); r[7] = (_Float16)(a7 * w);
      *(half8_t*)&At[wave * 16 + i][l << 3] = r;
    }
  }
  __syncthreads();

  // ---- phase 2: dual GEMM ----
  int arow = ms + l;
  bool valid = arow < n;
  f32x4 acc[8];
#pragma unroll
  for (int c = 0; c < 8; ++c) acc[c] = (f32x4){0.f, 0.f, 0.f, 0.f};

  // s=0: A = LDS agg tile
#pragma unroll
  for (int kb = 0; kb < 128; kb += 32) {
    half8_t af = *(const half8_t*)&At[wave * 16 + l][kb + g * 8];
#pragma unroll
    for (int c = 0; c < 8; ++c) {
      half8_t bf = *(const half8_t*)&Wh[(size_t)(c * 16 + l) * 128 + kb + g * 8];
      acc[c] = __builtin_amdgcn_mfma_f32_16x16x32_f16(af, bf, acc[c], 0, 0, 0);
    }
  }
  // s=1: A = root features from global
  {
    const _Float16* W2 = Wh + 16384;
    size_t abase = (size_t)arow * 128 + g * 8;
#pragma unroll
    for (int kb = 0; kb < 128; kb += 32) {
      half8_t af;
      if (valid) {
        af = *(const half8_t*)&hin[abase + kb];
      } else {
#pragma unroll
        for (int jj = 0; jj < 8; ++jj) af[jj] = (_Float16)0;
      }
#pragma unroll
      for (int c = 0; c < 8; ++c) {
        half8_t bf = *(const half8_t*)&W2[(size_t)(c * 16 + l) * 128 + kb + g * 8];
        acc[c] = __builtin_amdgcn_mfma_f32_16x16x32_f16(af, bf, acc[c], 0, 0, 0);
      }
    }
  }

  if (mode == 0) {
#pragma unroll
    for (int c = 0; c < 8; ++c) {
      float bcol = bias[c * 16 + l];
#pragma unroll
      for (int r = 0; r < 4; ++r) {
        int row = ms + g * 4 + r;
        if (row < n) {
          float v = fmaxf(acc[c][r] + bcol, 0.f);
          hout[(size_t)row * 128 + c * 16 + l] = (_Float16)v;
        }
      }
    }
  } else {
    // h3 = relu(acc + bias) -> LDS (own strip only), then head GEMM vs Wcat
    __syncthreads();
#pragma unroll
    for (int c = 0; c < 8; ++c) {
      float bcol = bias[c * 16 + l];
#pragma unroll
      for (int r = 0; r < 4; ++r) {
        float v = fmaxf(acc[c][r] + bcol, 0.f);
        At[wave * 16 + g * 4 + r][c * 16 + l] = (_Float16)v;
      }
    }
    __syncthreads();
    f32x4 ah = (f32x4){0.f, 0.f, 0.f, 0.f};
#pragma unroll
    for (int kb = 0; kb < 128; kb += 32) {
      half8_t af = *(const half8_t*)&At[wave * 16 + l][kb + g * 8];
      half8_t bf = *(const half8_t*)&Wcat[(size_t)l * 128 + kb + g * 8];
      ah = __builtin_amdgcn_mfma_f32_16x16x32_f16(af, bf, ah, 0, 0, 0);
    }
    float bcol = bcat[l];
#pragma unroll
    for (int r = 0; r < 4; ++r) {
      int row = ms + g * 4 + r;
      if (row < n) head_out[(size_t)row * 16 + l] = ah[r] + bcol;
    }
  }
}

// ---------------- 8-dim aggregation + output write ----------------
// out layout: age [n,3] @0, sex [n,2] @3n, eth [n,3] @5n
// Lane layout: g = lane>>2 picks one of 16 edge slots; c2 = lane&3 covers
// features 2*c2, 2*c2+1 via float2 loads. One instruction gathers 16 rows;
// main loop keeps 2 (32 edges) in flight. Branch-free masked tail.

__global__ void agg8_k(const float* __restrict__ hlr, const int* __restrict__ csr,
                       const int* __restrict__ row_start, const int* __restrict__ deg,
                       const float* __restrict__ invd, float* __restrict__ out, int n) {
  int node = (blockIdx.x << 2) + (threadIdx.x >> 6);
  if (node >= n) return;
  int lane = threadIdx.x & 63;
  int c2 = lane & 3;  // feature pair
  int g = lane >> 2;  // edge slot 0..15
  int s = row_start[node], cnt = deg[node];
  float ax = 0.f, ay = 0.f;
  int j = 0;
  for (; j + 32 <= cnt; j += 32) {
#pragma unroll
    for (int p = 0; p < 2; ++p) {
      int id = csr[s + j + 16 * p + g];
      float2 v = *(const float2*)&hlr[(size_t)id * 16 + 2 * c2];
      ax += v.x;
      ay += v.y;
    }
  }
  if (j < cnt) {
    int cm1 = cnt - 1;
#pragma unroll
    for (int p = 0; p < 2; ++p) {
      int e = j + 16 * p + g;
      float m = (e < cnt) ? 1.f : 0.f;
      int id = csr[s + min(e, cm1)];
      float2 v = *(const float2*)&hlr[(size_t)id * 16 + 2 * c2];
      ax = fmaf(m, v.x, ax);
      ay = fmaf(m, v.y, ay);
    }
  }
  ax += __shfl_xor(ax, 4);  ay += __shfl_xor(ay, 4);
  ax += __shfl_xor(ax, 8);  ay += __shfl_xor(ay, 8);
  ax += __shfl_xor(ax, 16); ay += __shfl_xor(ay, 16);
  ax += __shfl_xor(ax, 32); ay += __shfl_xor(ay, 32);
  if (g == 0) {
    float w = invd[node];
    float r0 = ax * w + hlr[(size_t)node * 16 + 8 + 2 * c2];
    float r1 = ay * w + hlr[(size_t)node * 16 + 8 + 2 * c2 + 1];
    float rr[2] = {r0, r1};
#pragma unroll
    for (int q = 0; q < 2; ++q) {
      int f = 2 * c2 + q;
      float r = rr[q];
      if (f < 3) out[(size_t)node * 3 + f] = r;
      else if (f < 5) out[(size_t)3 * n + (size_t)node * 2 + (f - 3)] = r;
      else out[(size_t)5 * n + (size_t)node * 3 + (f - 5)] = r;
    }
  }
}

// ---------------- launch ----------------

extern "C" void kernel_launch(void* const* d_in, const int* in_sizes, int n_in,
                              void* d_out, int out_size, void* d_ws, size_t ws_size,
                              hipStream_t stream) {
  const float* x = (const float*)d_in[0];
  const int* ei = (const int*)d_in[1];
  const float* W1l = (const float*)d_in[2];
  const float* W1r = (const float*)d_in[3];
  const float* b1 = (const float*)d_in[4];
  const float* W2l = (const float*)d_in[5];
  const float* W2r = (const float*)d_in[6];
  const float* b2 = (const float*)d_in[7];
  const float* W3l = (const float*)d_in[8];
  const float* W3r = (const float*)d_in[9];
  const float* b3 = (const float*)d_in[10];
  const float* Wal = (const float*)d_in[11];
  const float* War = (const float*)d_in[12];
  const float* ba = (const float*)d_in[13];
  const float* Wsl = (const float*)d_in[14];
  const float* Wsr = (const float*)d_in[15];
  const float* bsx = (const float*)d_in[16];
  const float* Wel = (const float*)d_in[17];
  const float* Wer = (const float*)d_in[18];
  const float* be = (const float*)d_in[19];

  int N = in_sizes[0] / 128;
  int E = in_sizes[1] / 2;
  int NBKT = (N + 255) >> 8;

  char* w = (char*)d_ws;
  auto alloc = [&](size_t b) {
    char* p = w;
    w += (b + 255) & ~(size_t)255;
    return p;
  };
  int* deg = (int*)alloc((size_t)N * 4);
  int* row_start = (int*)alloc((size_t)N * 4);
  float* invd = (float*)alloc((size_t)N * 4);
  int* hist = (int*)alloc((size_t)NBUCK * NB1 * 4);
  int* chunk = (int*)alloc(512 * 4);
  int* csr = (int*)alloc((size_t)E * 4);
  // xh (fp16 x, N*128*2 B) aliases ebuf (E*4 B): ebuf dead after build_k.
  size_t xh_bytes = (size_t)N * 128 * 2;
  size_t ebuf_bytes = (size_t)E * 4;
  char* region = (char*)alloc(xh_bytes > ebuf_bytes ? xh_bytes : ebuf_bytes);
  unsigned* ebuf = (unsigned*)region;
  _Float16* xh = (_Float16*)region;
  _Float16* hA = (_Float16*)alloc((size_t)N * 128 * 2);
  _Float16* hB = (_Float16*)alloc((size_t)N * 128 * 2);
  _Float16* wh = (_Float16*)alloc((size_t)6 * 16384 * 2);
  _Float16* Wcat = (_Float16*)alloc(2048 * 2);
  float* bcat = (float*)alloc(16 * 4);
  float* head_lr = (float*)alloc((size_t)N * 16 * 4);

  int stripe = (((E + NB1 - 1) / NB1) + 255) & ~255;
  int nscan = NBUCK * NB1;
  int nbScan = (nscan + TPB - 1) / TPB;
  int nbNode = (N + 3) / 4;
  int nbM = (N + 63) / 64;
  int nbC = (N * 32 + TPB - 1) / TPB;

  // CSR build — no global atomics
  hist1_k<<<NB1, 256, 0, stream>>>(ei, hist, E, stripe);
  scan1_k<<<nbScan, TPB, 0, stream>>>(hist, hist, chunk, nscan);
  scan2_k<<<1, 512, 0, stream>>>(chunk, nbScan);
  scan3_k<<<nbScan, TPB, 0, stream>>>(hist, chunk, nscan);
  scatter1_k<<<NB1, 256, 0, stream>>>(ei, hist, ebuf, E, stripe);
  build_k<<<NBKT, 256, 0, stream>>>(ebuf, hist, row_start, deg, invd, csr, N, E);

  // fp16 conversions (xh aliases ebuf: must come after build_k)
  f2h_k<<<nbC, TPB, 0, stream>>>(x, xh, N * 32);
  w6_k<<<96, TPB, 0, stream>>>(W1l, W1r, W2l, W2r, W3l, W3r, wh);
  pack_head_k<<<8, TPB, 0, stream>>>(Wal, War, ba, Wsl, Wsr, bsx, Wel, Wer, be, Wcat, bcat);

  // layer 1: x -> hA
  fused_sage_k<<<nbM, TPB, 0, stream>>>(xh, wh + 0 * 16384, b1, csr, row_start, deg,
                                        invd, hA, nullptr, nullptr, nullptr, N, 0);
  // layer 2: hA -> hB
  fused_sage_k<<<nbM, TPB, 0, stream>>>(hA, wh + 2 * 16384, b2, csr, row_start, deg,
                                        invd, hB, nullptr, nullptr, nullptr, N, 0);
  // layer 3 + heads: hB -> head_lr[n,16]
  fused_sage_k<<<nbM, TPB, 0, stream>>>(hB, wh + 4 * 16384, b3, csr, row_start, deg,
                                        invd, nullptr, Wcat, bcat, head_lr, N, 1);
  // final 8-dim neighbor aggregation + output
  agg8_k<<<nbNode, TPB, 0, stream>>>(head_lr, csr, row_start, deg, invd, (float*)d_out, N);
}

// Round 3
// 688.445 us; speedup vs baseline: 1.2078x; 1.1364x over previous
//
#include <hip/hip_runtime.h>

#define TPB 256
#define NB1 256    // stripe blocks for edge passes
#define NBUCK 512  // coarse buckets (dst>>8); supports N <= 131072

using half4_t = __attribute__((ext_vector_type(4))) _Float16;
using half8_t = __attribute__((ext_vector_type(8))) _Float16;
using f32x4 = __attribute__((ext_vector_type(4))) float;

// ---------------- CSR build: atomic-free MSD counting sort ----------------

__global__ __launch_bounds__(256) void hist1_k(const int* __restrict__ ei,
                                               int* __restrict__ hist, int E, int stripe) {
  __shared__ int h[NBUCK];
  for (int i = threadIdx.x; i < NBUCK; i += 256) h[i] = 0;
  __syncthreads();
  int b0 = blockIdx.x * stripe;
  int b1 = min(b0 + stripe, E);
  for (int e = b0 + threadIdx.x; e < b1; e += 256) atomicAdd(&h[ei[E + e] >> 8], 1);
  __syncthreads();
  for (int i = threadIdx.x; i < NBUCK; i += 256) hist[i * NB1 + blockIdx.x] = h[i];
}

__global__ void scan1_k(const int* __restrict__ src, int* __restrict__ out,
                        int* __restrict__ chunk, int n) {
  __shared__ int sh[TPB];
  int i = blockIdx.x * TPB + threadIdx.x;
  int v = (i < n) ? src[i] : 0;
  sh[threadIdx.x] = v;
  __syncthreads();
  for (int off = 1; off < TPB; off <<= 1) {
    int t = (threadIdx.x >= off) ? sh[threadIdx.x - off] : 0;
    __syncthreads();
    sh[threadIdx.x] += t;
    __syncthreads();
  }
  if (i < n) out[i] = sh[threadIdx.x] - v;
  if (threadIdx.x == TPB - 1) chunk[blockIdx.x] = sh[TPB - 1];
}

__global__ void scan2_k(int* __restrict__ chunk, int nb) {
  __shared__ int sh[512];
  int v = (threadIdx.x < nb) ? chunk[threadIdx.x] : 0;
  sh[threadIdx.x] = v;
  __syncthreads();
  for (int off = 1; off < 512; off <<= 1) {
    int t = (threadIdx.x >= off) ? sh[threadIdx.x - off] : 0;
    __syncthreads();
    sh[threadIdx.x] += t;
    __syncthreads();
  }
  if (threadIdx.x < nb) chunk[threadIdx.x] = sh[threadIdx.x] - v;
}

__global__ void scan3_k(int* __restrict__ out, const int* __restrict__ chunk, int n) {
  int i = blockIdx.x * TPB + threadIdx.x;
  if (i < n) out[i] += chunk[blockIdx.x];
}

// pack: src (24 bits) | low8(dst) << 24
__global__ __launch_bounds__(256) void scatter1_k(const int* __restrict__ ei,
                                                  const int* __restrict__ base,
                                                  unsigned* __restrict__ ebuf, int E,
                                                  int stripe) {
  __shared__ int cur[NBUCK];
  for (int i = threadIdx.x; i < NBUCK; i += 256) cur[i] = base[i * NB1 + blockIdx.x];
  __syncthreads();
  int b0 = blockIdx.x * stripe;
  int b1 = min(b0 + stripe, E);
  for (int e = b0 + threadIdx.x; e < b1; e += 256) {
    int s = ei[e];
    int d = ei[E + e];
    int p = atomicAdd(&cur[d >> 8], 1);
    ebuf[p] = (unsigned)s | ((unsigned)(d & 255) << 24);
  }
}

__global__ __launch_bounds__(256) void build_k(const unsigned* __restrict__ ebuf,
                                               const int* __restrict__ base,
                                               int* __restrict__ row_start,
                                               int* __restrict__ deg,
                                               float* __restrict__ invd,
                                               int* __restrict__ csr, int N, int E) {
  __shared__ int h[256];
  __shared__ int excl[256];
  __shared__ int bse[2];
  int b = blockIdx.x;
  int t = threadIdx.x;
  if (t == 0) {
    bse[0] = base[b * NB1];
    bse[1] = (b + 1 < NBUCK) ? base[(b + 1) * NB1] : E;
  }
  h[t] = 0;
  __syncthreads();
  int bs = bse[0], be = bse[1];
  for (int e = bs + t; e < be; e += 256) atomicAdd(&h[ebuf[e] >> 24], 1);
  __syncthreads();
  int v = h[t];
  excl[t] = v;
  __syncthreads();
  for (int off = 1; off < 256; off <<= 1) {
    int tv = (t >= off) ? excl[t - off] : 0;
    __syncthreads();
    excl[t] += tv;
    __syncthreads();
  }
  int ex = excl[t] - v;
  int node = b * 256 + t;
  if (node < N) {
    row_start[node] = bs + ex;
    deg[node] = v;
    invd[node] = 1.0f / fmaxf((float)v, 1.0f);
  }
  h[t] = bs + ex;
  __syncthreads();
  for (int e = bs + t; e < be; e += 256) {
    unsigned p = ebuf[e];
    int pos = atomicAdd(&h[p >> 24], 1);
    csr[pos] = (int)(p & 0xFFFFFFu);
  }
}

// ---------------- fp32 -> fp16 converts ----------------

__global__ void f2h_k(const float* __restrict__ in, _Float16* __restrict__ out, int n4) {
  int i = blockIdx.x * TPB + threadIdx.x;
  if (i < n4) {
    float4 v = ((const float4*)in)[i];
    half4_t o;
    o.x = (_Float16)v.x; o.y = (_Float16)v.y; o.z = (_Float16)v.z; o.w = (_Float16)v.w;
    ((half4_t*)out)[i] = o;
  }
}

// Convert the 6 layer weight matrices (each 128x128) to fp16, packed
// [W1l, W1r, W2l, W2r, W3l, W3r] at 16384-element strides.
__global__ void w6_k(const float* __restrict__ w0, const float* __restrict__ w1,
                     const float* __restrict__ w2, const float* __restrict__ w3,
                     const float* __restrict__ w4, const float* __restrict__ w5,
                     _Float16* __restrict__ out) {
  int t = blockIdx.x * TPB + threadIdx.x;  // t < 6*4096 (float4 units)
  if (t >= 6 * 4096) return;
  int which = t >> 12, i = t & 4095;
  const float* src = which == 0 ? w0 : which == 1 ? w1 : which == 2 ? w2
                   : which == 3 ? w3 : which == 4 ? w4 : w5;
  float4 v = ((const float4*)src)[i];
  half4_t o;
  o.x = (_Float16)v.x; o.y = (_Float16)v.y; o.z = (_Float16)v.z; o.w = (_Float16)v.w;
  ((half4_t*)out)[(size_t)which * 4096 + i] = o;
}

// ---------------- head weight packing (fp16 Wcat, fp32 bcat) ----------------

__global__ void pack_head_k(const float* __restrict__ Wal, const float* __restrict__ War,
                            const float* __restrict__ ba, const float* __restrict__ Wsl,
                            const float* __restrict__ Wsr, const float* __restrict__ bsx,
                            const float* __restrict__ Wel, const float* __restrict__ Wer,
                            const float* __restrict__ be, _Float16* __restrict__ Wcat,
                            float* __restrict__ bcat) {
  int t = blockIdx.x * TPB + threadIdx.x;
  float v = 0.f;
  bool ok = t < 2048;
  if (t < 384) v = Wal[t];
  else if (t < 640) v = Wsl[t - 384];
  else if (t < 1024) v = Wel[t - 640];
  else if (t < 1408) v = War[t - 1024];
  else if (t < 1664) v = Wsr[t - 1408];
  else if (t < 2048) v = Wer[t - 1664];
  if (ok) Wcat[t] = (_Float16)v;
  if (t < 16) {
    float b = 0.f;
    if (t >= 8 && t < 11) b = ba[t - 8];
    else if (t >= 11 && t < 13) b = bsx[t - 11];
    else if (t >= 13) b = be[t - 13];
    bcat[t] = b;
  }
}

// ---------------- fused SAGE layer: gather-mean -> LDS -> dual MFMA GEMM ----------------
// Block = 4 waves = 16-node tile (grid = N/16 = 6250 blocks: ~3 refill rounds,
// full residency — R2's 64-node tile starved the machine at 1563 blocks).
// Phase 1 (gather): each wave mean-aggregates 4 nodes (short serial chain) into
//   the LDS A-tile. Lane layout per node: g=lane>>4 picks edge slot 0..3,
//   l=lane&15 covers features l*8..l*8+7 (half8, 16 B). 4 rows/instruction,
//   4 KB in flight. (row_start,deg) for all 4 nodes preloaded; node i+1's
//   first csr chunk prefetched before node i's tail+reduce.
// Phase 2 (GEMM): wave computes 16 rows x 32 cols (2 c-tiles of 16x16x32 MFMA,
//   cols wave*32..wave*32+31); s=0 A from LDS (agg), s=1 A from global (root).
//   C layout: col=lane&15, row=quad*4+reg (m89-verified).
// mode 0: out = relu(...) -> hout (fp16 [n][128])
// mode 1: h3 = relu(...) -> LDS; head_out[n][16] = h3 @ Wcat^T + bcat (fp32)
// LDS row stride 144 halfs (288 B): 16B-aligned, 4-way-max bank aliasing.

__global__ __launch_bounds__(256) void fused_sage_k(
    const _Float16* __restrict__ hin, const _Float16* __restrict__ Wh,
    const float* __restrict__ bias, const int* __restrict__ csr,
    const int* __restrict__ row_start, const int* __restrict__ deg,
    const float* __restrict__ invd, _Float16* __restrict__ hout,
    const _Float16* __restrict__ Wcat, const float* __restrict__ bcat,
    float* __restrict__ head_out, int n, int mode) {
  __shared__ _Float16 At[16][144];
  int wave = threadIdx.x >> 6;
  int lane = threadIdx.x & 63;
  int g = lane >> 4;  // edge slot / quad
  int l = lane & 15;  // feature lane / l16
  int ms = blockIdx.x * 16;  // block's tile base row

  // ---- phase 1: mean-aggregate 4 nodes per wave into LDS ----
  const _Float16* gbase = hin + (l << 3);
  int nb = ms + wave * 4;
  int rs[4], dg[4];
#pragma unroll
  for (int i = 0; i < 4; ++i) {
    int nd = nb + i;
    bool ok = nd < n;
    rs[i] = ok ? row_start[nd] : 0;
    dg[i] = ok ? deg[nd] : 0;
  }
  int nid[4];
  if (dg[0] >= 16) {
#pragma unroll
    for (int p = 0; p < 4; ++p) nid[p] = csr[rs[0] + 4 * p + g];
  }
  for (int i = 0; i < 4; ++i) {
    int s = rs[i], c = dg[i];
    float a0 = 0.f, a1 = 0.f, a2 = 0.f, a3 = 0.f;
    float a4 = 0.f, a5 = 0.f, a6 = 0.f, a7 = 0.f;
    int j = 0;
    if (c >= 16) {
      int id[4];
#pragma unroll
      for (int p = 0; p < 4; ++p) id[p] = nid[p];
      while (true) {
        half8_t v[4];
#pragma unroll
        for (int p = 0; p < 4; ++p) v[p] = *(const half8_t*)&gbase[(size_t)id[p] * 128];
        j += 16;
        bool more = (j + 16 <= c);
        if (more) {
#pragma unroll
          for (int p = 0; p < 4; ++p) id[p] = csr[s + j + 4 * p + g];
        }
#pragma unroll
        for (int p = 0; p < 4; ++p) {
          a0 += (float)v[p][0]; a1 += (float)v[p][1];
          a2 += (float)v[p][2]; a3 += (float)v[p][3];
          a4 += (float)v[p][4]; a5 += (float)v[p][5];
          a6 += (float)v[p][6]; a7 += (float)v[p][7];
        }
        if (!more) break;
      }
    }
    // prefetch next node's first chunk (hides its idx latency under tail+reduce)
    if (i < 3 && dg[i + 1] >= 16) {
#pragma unroll
      for (int p = 0; p < 4; ++p) nid[p] = csr[rs[i + 1] + 4 * p + g];
    }
    if (j < c) {  // masked tail: 0..15 edges, all loads issued together
      int cm1 = c - 1;
#pragma unroll
      for (int p = 0; p < 4; ++p) {
        int e = j + 4 * p + g;
        float m = (e < c) ? 1.f : 0.f;
        int id = csr[s + min(e, cm1)];
        half8_t v = *(const half8_t*)&gbase[(size_t)id * 128];
        a0 = fmaf(m, (float)v[0], a0); a1 = fmaf(m, (float)v[1], a1);
        a2 = fmaf(m, (float)v[2], a2); a3 = fmaf(m, (float)v[3], a3);
        a4 = fmaf(m, (float)v[4], a4); a5 = fmaf(m, (float)v[5], a5);
        a6 = fmaf(m, (float)v[6], a6); a7 = fmaf(m, (float)v[7], a7);
      }
    }
    // reduce across the 4 edge slots (lanes l, l+16, l+32, l+48)
    a0 += __shfl_xor(a0, 16); a1 += __shfl_xor(a1, 16);
    a2 += __shfl_xor(a2, 16); a3 += __shfl_xor(a3, 16);
    a4 += __shfl_xor(a4, 16); a5 += __shfl_xor(a5, 16);
    a6 += __shfl_xor(a6, 16); a7 += __shfl_xor(a7, 16);
    a0 += __shfl_xor(a0, 32); a1 += __shfl_xor(a1, 32);
    a2 += __shfl_xor(a2, 32); a3 += __shfl_xor(a3, 32);
    a4 += __shfl_xor(a4, 32); a5 += __shfl_xor(a5, 32);
    a6 += __shfl_xor(a6, 32); a7 += __shfl_xor(a7, 32);
    if (g == 0) {
      int node = nb + i;
      float w = (node < n) ? invd[node] : 0.f;
      half8_t r;
      r[0] = (_Float16)(a0 * w); r[1] = (_Float16)(a1 * w);
      r[2] = (_Float16)(a2 * w); r[3] = (_Float16)(a3 * w);
      r[4] = (_Float16)(a4 * w); r[5] = (_Float16)(a5 * w);
      r[6] = (_Float16)(a6 * w); r[7] = (_Float16)(a7 * w);
      *(half8_t*)&At[wave * 4 + i][l << 3] = r;
    }
  }
  __syncthreads();

  // ---- phase 2: dual GEMM; wave covers cols wave*32..wave*32+31 ----
  int arow = ms + l;
  bool valid = arow < n;
  f32x4 acc[2];
  acc[0] = (f32x4){0.f, 0.f, 0.f, 0.f};
  acc[1] = (f32x4){0.f, 0.f, 0.f, 0.f};

  // s=0: A = LDS agg tile
#pragma unroll
  for (int kb = 0; kb < 128; kb += 32) {
    half8_t af = *(const half8_t*)&At[l][kb + g * 8];
#pragma unroll
    for (int ct = 0; ct < 2; ++ct) {
      int ocol = wave * 32 + ct * 16 + l;
      half8_t bf = *(const half8_t*)&Wh[(size_t)ocol * 128 + kb + g * 8];
      acc[ct] = __builtin_amdgcn_mfma_f32_16x16x32_f16(af, bf, acc[ct], 0, 0, 0);
    }
  }
  // s=1: A = root features from global
  {
    const _Float16* W2 = Wh + 16384;
    size_t abase = (size_t)arow * 128 + g * 8;
#pragma unroll
    for (int kb = 0; kb < 128; kb += 32) {
      half8_t af;
      if (valid) {
        af = *(const half8_t*)&hin[abase + kb];
      } else {
#pragma unroll
        for (int jj = 0; jj < 8; ++jj) af[jj] = (_Float16)0;
      }
#pragma unroll
      for (int ct = 0; ct < 2; ++ct) {
        int ocol = wave * 32 + ct * 16 + l;
        half8_t bf = *(const half8_t*)&W2[(size_t)ocol * 128 + kb + g * 8];
        acc[ct] = __builtin_amdgcn_mfma_f32_16x16x32_f16(af, bf, acc[ct], 0, 0, 0);
      }
    }
  }

  if (mode == 0) {
#pragma unroll
    for (int ct = 0; ct < 2; ++ct) {
      int col = wave * 32 + ct * 16 + l;
      float bcol = bias[col];
#pragma unroll
      for (int r = 0; r < 4; ++r) {
        int row = ms + g * 4 + r;
        if (row < n) {
          float v = fmaxf(acc[ct][r] + bcol, 0.f);
          hout[(size_t)row * 128 + col] = (_Float16)v;
        }
      }
    }
  } else {
    // h3 = relu(acc + bias) -> LDS, then head GEMM vs Wcat (wave 0 only)
    __syncthreads();
#pragma unroll
    for (int ct = 0; ct < 2; ++ct) {
      int col = wave * 32 + ct * 16 + l;
      float bcol = bias[col];
#pragma unroll
      for (int r = 0; r < 4; ++r) {
        float v = fmaxf(acc[ct][r] + bcol, 0.f);
        At[g * 4 + r][col] = (_Float16)v;
      }
    }
    __syncthreads();
    if (wave == 0) {
      f32x4 ah = (f32x4){0.f, 0.f, 0.f, 0.f};
#pragma unroll
      for (int kb = 0; kb < 128; kb += 32) {
        half8_t af = *(const half8_t*)&At[l][kb + g * 8];
        half8_t bf = *(const half8_t*)&Wcat[(size_t)l * 128 + kb + g * 8];
        ah = __builtin_amdgcn_mfma_f32_16x16x32_f16(af, bf, ah, 0, 0, 0);
      }
      float bcol = bcat[l];
#pragma unroll
      for (int r = 0; r < 4; ++r) {
        int row = ms + g * 4 + r;
        if (row < n) head_out[(size_t)row * 16 + l] = ah[r] + bcol;
      }
    }
  }
}

// ---------------- 8-dim aggregation + output write ----------------
// out layout: age [n,3] @0, sex [n,2] @3n, eth [n,3] @5n
// Lane layout: g = lane>>2 picks one of 16 edge slots; c2 = lane&3 covers
// features 2*c2, 2*c2+1 via float2 loads. One instruction gathers 16 rows;
// main loop keeps 2 (32 edges) in flight. Branch-free masked tail.

__global__ void agg8_k(const float* __restrict__ hlr, const int* __restrict__ csr,
                       const int* __restrict__ row_start, const int* __restrict__ deg,
                       const float* __restrict__ invd, float* __restrict__ out, int n) {
  int node = (blockIdx.x << 2) + (threadIdx.x >> 6);
  if (node >= n) return;
  int lane = threadIdx.x & 63;
  int c2 = lane & 3;  // feature pair
  int g = lane >> 2;  // edge slot 0..15
  int s = row_start[node], cnt = deg[node];
  float ax = 0.f, ay = 0.f;
  int j = 0;
  for (; j + 32 <= cnt; j += 32) {
#pragma unroll
    for (int p = 0; p < 2; ++p) {
      int id = csr[s + j + 16 * p + g];
      float2 v = *(const float2*)&hlr[(size_t)id * 16 + 2 * c2];
      ax += v.x;
      ay += v.y;
    }
  }
  if (j < cnt) {
    int cm1 = cnt - 1;
#pragma unroll
    for (int p = 0; p < 2; ++p) {
      int e = j + 16 * p + g;
      float m = (e < cnt) ? 1.f : 0.f;
      int id = csr[s + min(e, cm1)];
      float2 v = *(const float2*)&hlr[(size_t)id * 16 + 2 * c2];
      ax = fmaf(m, v.x, ax);
      ay = fmaf(m, v.y, ay);
    }
  }
  ax += __shfl_xor(ax, 4);  ay += __shfl_xor(ay, 4);
  ax += __shfl_xor(ax, 8);  ay += __shfl_xor(ay, 8);
  ax += __shfl_xor(ax, 16); ay += __shfl_xor(ay, 16);
  ax += __shfl_xor(ax, 32); ay += __shfl_xor(ay, 32);
  if (g == 0) {
    float w = invd[node];
    float r0 = ax * w + hlr[(size_t)node * 16 + 8 + 2 * c2];
    float r1 = ay * w + hlr[(size_t)node * 16 + 8 + 2 * c2 + 1];
    float rr[2] = {r0, r1};
#pragma unroll
    for (int q = 0; q < 2; ++q) {
      int f = 2 * c2 + q;
      float r = rr[q];
      if (f < 3) out[(size_t)node * 3 + f] = r;
      else if (f < 5) out[(size_t)3 * n + (size_t)node * 2 + (f - 3)] = r;
      else out[(size_t)5 * n + (size_t)node * 3 + (f - 5)] = r;
    }
  }
}

// ---------------- launch ----------------

extern "C" void kernel_launch(void* const* d_in, const int* in_sizes, int n_in,
                              void* d_out, int out_size, void* d_ws, size_t ws_size,
                              hipStream_t stream) {
  const float* x = (const float*)d_in[0];
  const int* ei = (const int*)d_in[1];
  const float* W1l = (const float*)d_in[2];
  const float* W1r = (const float*)d_in[3];
  const float* b1 = (const float*)d_in[4];
  const float* W2l = (const float*)d_in[5];
  const float* W2r = (const float*)d_in[6];
  const float* b2 = (const float*)d_in[7];
  const float* W3l = (const float*)d_in[8];
  const float* W3r = (const float*)d_in[9];
  const float* b3 = (const float*)d_in[10];
  const float* Wal = (const float*)d_in[11];
  const float* War = (const float*)d_in[12];
  const float* ba = (const float*)d_in[13];
  const float* Wsl = (const float*)d_in[14];
  const float* Wsr = (const float*)d_in[15];
  const float* bsx = (const float*)d_in[16];
  const float* Wel = (const float*)d_in[17];
  const float* Wer = (const float*)d_in[18];
  const float* be = (const float*)d_in[19];

  int N = in_sizes[0] / 128;
  int E = in_sizes[1] / 2;
  int NBKT = (N + 255) >> 8;

  char* w = (char*)d_ws;
  auto alloc = [&](size_t b) {
    char* p = w;
    w += (b + 255) & ~(size_t)255;
    return p;
  };
  int* deg = (int*)alloc((size_t)N * 4);
  int* row_start = (int*)alloc((size_t)N * 4);
  float* invd = (float*)alloc((size_t)N * 4);
  int* hist = (int*)alloc((size_t)NBUCK * NB1 * 4);
  int* chunk = (int*)alloc(512 * 4);
  int* csr = (int*)alloc((size_t)E * 4);
  // xh (fp16 x, N*128*2 B) aliases ebuf (E*4 B): ebuf dead after build_k.
  size_t xh_bytes = (size_t)N * 128 * 2;
  size_t ebuf_bytes = (size_t)E * 4;
  char* region = (char*)alloc(xh_bytes > ebuf_bytes ? xh_bytes : ebuf_bytes);
  unsigned* ebuf = (unsigned*)region;
  _Float16* xh = (_Float16*)region;
  _Float16* hA = (_Float16*)alloc((size_t)N * 128 * 2);
  _Float16* hB = (_Float16*)alloc((size_t)N * 128 * 2);
  _Float16* wh = (_Float16*)alloc((size_t)6 * 16384 * 2);
  _Float16* Wcat = (_Float16*)alloc(2048 * 2);
  float* bcat = (float*)alloc(16 * 4);
  float* head_lr = (float*)alloc((size_t)N * 16 * 4);

  int stripe = (((E + NB1 - 1) / NB1) + 255) & ~255;
  int nscan = NBUCK * NB1;
  int nbScan = (nscan + TPB - 1) / TPB;
  int nbNode = (N + 3) / 4;
  int nbM = (N + 15) / 16;
  int nbC = (N * 32 + TPB - 1) / TPB;

  // CSR build — no global atomics
  hist1_k<<<NB1, 256, 0, stream>>>(ei, hist, E, stripe);
  scan1_k<<<nbScan, TPB, 0, stream>>>(hist, hist, chunk, nscan);
  scan2_k<<<1, 512, 0, stream>>>(chunk, nbScan);
  scan3_k<<<nbScan, TPB, 0, stream>>>(hist, chunk, nscan);
  scatter1_k<<<NB1, 256, 0, stream>>>(ei, hist, ebuf, E, stripe);
  build_k<<<NBKT, 256, 0, stream>>>(ebuf, hist, row_start, deg, invd, csr, N, E);

  // fp16 conversions (xh aliases ebuf: must come after build_k)
  f2h_k<<<nbC, TPB, 0, stream>>>(x, xh, N * 32);
  w6_k<<<96, TPB, 0, stream>>>(W1l, W1r, W2l, W2r, W3l, W3r, wh);
  pack_head_k<<<8, TPB, 0, stream>>>(Wal, War, ba, Wsl, Wsr, bsx, Wel, Wer, be, Wcat, bcat);

  // layer 1: x -> hA
  fused_sage_k<<<nbM, TPB, 0, stream>>>(xh, wh + 0 * 16384, b1, csr, row_start, deg,
                                        invd, hA, nullptr, nullptr, nullptr, N, 0);
  // layer 2: hA -> hB
  fused_sage_k<<<nbM, TPB, 0, stream>>>(hA, wh + 2 * 16384, b2, csr, row_start, deg,
                                        invd, hB, nullptr, nullptr, nullptr, N, 0);
  // layer 3 + heads: hB -> head_lr[n,16]
  fused_sage_k<<<nbM, TPB, 0, stream>>>(hB, wh + 4 * 16384, b3, csr, row_start, deg,
                                        invd, nullptr, Wcat, bcat, head_lr, N, 1);
  // final 8-dim neighbor aggregation + output
  agg8_k<<<nbNode, TPB, 0, stream>>>(head_lr, csr, row_start, deg, invd, (float*)d_out, N);
}